// Round 13
// baseline (523.668 us; speedup 1.0000x reference)
//
#include <hip/hip_runtime.h>
#include <hip/hip_bf16.h>
#include <math.h>

// Problem constants
#define NN 20000
#define MM 20          // neighbors (same for che and vdw)
#define EE 20          // RBF size
#define HH 128
#define BB 200
#define NCONV 3
#define CHE_CUT 8.0f
#define VDW_CUT 12.0f
#define PI_F 3.14159265358979323846f
#define LOG2E_F 1.44269504088896340736f
#define LN2_F 0.69314718055994530942f

// __builtin_amdgcn_cvt_pkrtz / __builtin_amdgcn_fdot2 use __fp16 vectors
typedef __fp16 half2_t __attribute__((ext_vector_type(2)));
// MFMA f16 builtins use _Float16 vectors
typedef _Float16 f16x8 __attribute__((ext_vector_type(8)));
typedef float f32x4 __attribute__((ext_vector_type(4)));

// ---------------- helpers ---------------------------------------------------
__device__ __forceinline__ float exp2_(float x) {
#if __has_builtin(__builtin_amdgcn_exp2f)
    return __builtin_amdgcn_exp2f(x);
#else
    return exp2f(x);
#endif
}
__device__ __forceinline__ float log2_(float x) {
#if __has_builtin(__builtin_amdgcn_logf)
    return __builtin_amdgcn_logf(x);
#else
    return log2f(x);
#endif
}
__device__ __forceinline__ float rcp_(float x) {
#if __has_builtin(__builtin_amdgcn_rcpf)
    return __builtin_amdgcn_rcpf(x);
#else
    return 1.f / x;
#endif
}
__device__ __forceinline__ float sp_(float x) {      // natural-domain softplus
    return (x > 15.f) ? x : LN2_F * log2_(1.f + exp2_(x * LOG2E_F));
}
__device__ __forceinline__ float fdot2_(half2_t a, half2_t b, float c) {
#if __has_builtin(__builtin_amdgcn_fdot2)
    return __builtin_amdgcn_fdot2(a, b, c, false);
#else
    return (float)a.x * (float)b.x + (float)a.y * (float)b.y + c;
#endif
}

// ---------------- prep: bc = (gb + fb @ gW_edge) * log2e --------------------
// bc layout: [l][half][gate*128+t] fp32
__global__ void prep_bias(const float* __restrict__ cfb, const float* __restrict__ cgW,
                          const float* __restrict__ cgb,
                          const float* __restrict__ vfb, const float* __restrict__ vgW,
                          const float* __restrict__ vgb, float* __restrict__ bc) {
    int half = blockIdx.y;
    int l = blockIdx.z;
    int j = threadIdx.x;         // 0..255
    const float* fb = half ? vfb : cfb;
    const float* gW = half ? vgW : cgW;
    const float* gb = half ? vgb : cgb;
    const float* gWe = gW + ((size_t)l * 384 + 128) * 256;
    const float* brow = fb + (size_t)l * HH;
    float acc = gb[(size_t)l * 256 + j];
    for (int k = 0; k < HH; ++k) acc = fmaf(brow[k], gWe[k * 256 + j], acc);
    bc[((size_t)l * 2 + half) * 256 + j] = acc * LOG2E_F;
}

// ---------------- prep: bwc — Wc=fW@gW_edge in MFMA B-fragment order --------
// PAIRED TILES: nt 0..7 = filt cols (t = nt*16+nc), nt 8..15 = core cols
// (same t) -> a wave computing tiles (p, 8+p) holds filt(t)/core(t) in ONE
// lane -> local cvt_pkrtz pack, no cross-lane traffic.
// k = e (0..19), pad 20..31 ZERO.
// bwc[l][h][nt(16)][lane(64)][8]: lane = (k>>3)*16 + nc, j = k&7
__global__ void prep_bwc(const float* __restrict__ cfW, const float* __restrict__ cgW,
                         const float* __restrict__ vfW, const float* __restrict__ vgW,
                         _Float16* __restrict__ bwc) {
    int nt = blockIdx.x;         // 0..15
    int half = blockIdx.y;
    int l = blockIdx.z;
    int tid = threadIdx.x;       // 0..511: k = tid>>4, nc = tid&15
    int k = tid >> 4, nc = tid & 15;
    int t = (nt & 7) * 16 + nc;          // 0..127
    int gcol = (nt >> 3) * 128 + t;      // filt: 0..127, core: 128..255
    const float* fW = half ? vfW : cfW;
    const float* gW = half ? vgW : cgW;
    const float* gWe = gW + ((size_t)l * 384 + 128) * 256;
    float val = 0.f;
    if (k < EE) {
        const float* frow = fW + ((size_t)l * EE + k) * HH;
        for (int kk = 0; kk < HH; ++kk) val = fmaf(frow[kk], gWe[kk * 256 + gcol], val);
        val *= LOG2E_F;
    }
    bwc[(((size_t)(l * 2 + half) * 16 + nt) * 64 + (k >> 3) * 16 + nc) * 8 + (k & 7)] = (_Float16)val;
}

// ---------------- prep: Bpk — B in MFMA B-fragment order, f16, x log2e ------
// column order (identity regions): [cheS|vdwS|cheY|vdwY]
__global__ void prep_bpk(const float* __restrict__ cgW, const float* __restrict__ vgW,
                         _Float16* __restrict__ bpk) {
    int i = blockIdx.x * 256 + threadIdx.x;
    if (i >= NCONV * 128 * 1024) return;
    int l = i >> 17;
    int rem = i & 131071;
    int k = rem >> 10;         // 0..127
    int c = rem & 1023;
    int half = (c >> 8) & 1;   // regions: che,vdw,che,vdw
    const float* src = half ? vgW : cgW;
    int grow = l * 384 + ((c < 512) ? k : 256 + k);
    float val = src[(size_t)grow * 256 + (c & 255)] * LOG2E_F;
    int nt = c >> 4, nc = c & 15;
    int s = k >> 5, kq = (k >> 3) & 3, j = k & 7;
    bpk[(size_t)l * 131072 + (((size_t)nt * 4 + s) * 64 + kq * 16 + nc) * 8 + j] = (_Float16)val;
}

// ---------------- embed: f32 nodes + f16 copy for the GEMM ------------------
__global__ void embed_kernel(const float* __restrict__ atoms, const float* __restrict__ W,
                             const float* __restrict__ bias, float* __restrict__ nodes,
                             _Float16* __restrict__ nodes_h) {
    int n = blockIdx.x, t = threadIdx.x;
    const float* arow = atoms + (size_t)n * 13;
    float acc = bias[t];
    #pragma unroll
    for (int k = 0; k < 13; ++k) acc = fmaf(arow[k], W[k * HH + t], acc);
    nodes[(size_t)n * HH + t] = acc;
    nodes_h[(size_t)n * HH + t] = (_Float16)acc;
}

// ---------------- rbf: write straight into per-node A-fragment order --------
// rfrag[h][n][mt(2)][lane(64)][8] f16;  A[m][k]: m=(lane&15)+16*mt, k=(lane>>4)*8+j
// k=20..31 explicit zeros; mt=1 rows 20..31 zero-filled by hipMemsetAsync.
__global__ void rbf_kernel(const float* __restrict__ che_fea, const float* __restrict__ vdw_fea,
                           _Float16* __restrict__ rfrag) {
    int i = blockIdx.x * blockDim.x + threadIdx.x;
    if (i >= 2 * NN * MM) return;
    bool isv = i >= NN * MM;
    int rem = isv ? i - NN * MM : i;
    int n = rem / MM, m = rem % MM;
    float d = isv ? vdw_fea[rem] : che_fea[rem];
    float cutoff = isv ? VDW_CUT : CHE_CUT;
    float x = d * (PI_F / cutoff);
    float s1 = sinf(x), c1 = cosf(x);
    float env = 0.5f * (c1 + 1.f);
    float scale = (d < cutoff) ? (env / d) : 0.f;
    float out[EE];
    float skm1 = 0.f, sk = s1;
    #pragma unroll
    for (int e = 0; e < EE; ++e) {
        out[e] = sk * scale;
        float nx = 2.f * c1 * sk - skm1;
        skm1 = sk; sk = nx;
    }
    int mt = m >> 4, la = m & 15;
    _Float16* base = rfrag + (((size_t)(isv ? NN + n : n) * 2 + mt) * 64) * 8 + la * 8;
    f16x8 v0, v1, v2, v3;
    #pragma unroll
    for (int j = 0; j < 8; ++j) {
        v0[j] = (_Float16)out[j];
        v1[j] = (_Float16)out[8 + j];
        v2[j] = (j < 4) ? (_Float16)out[16 + j] : (_Float16)0.f;
        v3[j] = (_Float16)0.f;
    }
    *(f16x8*)(base) = v0;             // quad 0 (k 0..7)
    *(f16x8*)(base + 128) = v1;       // quad 1 (k 8..15)
    *(f16x8*)(base + 256) = v2;       // quad 2 (k 16..23, 20+ zero)
    *(f16x8*)(base + 384) = v3;       // quad 3 (k 24..31, zero)
}

// ---------------- SY GEMM via MFMA: [N,128]@[128,1024] -> Spk + Ypk f16x2 ---
// 1250 blocks x 4 waves; M=16 rows/block. Wave wv handles gate pair tiles
// (wv*16+p, wv*16+8+p), p=0..7 -> (filt,core) of one channel in SAME lane.
// wv 0: che-S, 1: vdw-S, 2: che-Y, 3: vdw-Y. All values pre-scaled by log2e.
__global__ __launch_bounds__(256)
void gemm_mfma(const _Float16* __restrict__ Ah, const _Float16* __restrict__ Bpk,
               half2_t* __restrict__ Spk, half2_t* __restrict__ Ypk) {
    int lane = threadIdx.x & 63;
    int wv = threadIdx.x >> 6;       // 0..3
    int m0 = blockIdx.x * 16;
    int la = lane & 15;
    int quad = lane >> 4;
    int k0 = quad * 8;

    f16x8 af[4];
    {
        const _Float16* arow = Ah + (size_t)(m0 + la) * 128 + k0;
        #pragma unroll
        for (int s = 0; s < 4; ++s)
            af[s] = *(const f16x8*)(arow + s * 32);
    }

    const f16x8* bp = (const f16x8*)Bpk;
    int ntf0 = wv * 16;
    half2_t* dst = (wv & 2) ? Ypk : Spk;
    int wbase = (wv & 1) * 128 + la;

    f16x8 fb[4], cb[4], nfb[4], ncb[4];
    #pragma unroll
    for (int s = 0; s < 4; ++s) {
        fb[s] = bp[((size_t)ntf0 * 4 + s) * 64 + lane];
        cb[s] = bp[((size_t)(ntf0 + 8) * 4 + s) * 64 + lane];
    }
    for (int p = 0; p < 8; ++p) {
        if (p < 7) {
            #pragma unroll
            for (int s = 0; s < 4; ++s) {
                nfb[s] = bp[((size_t)(ntf0 + p + 1) * 4 + s) * 64 + lane];
                ncb[s] = bp[((size_t)(ntf0 + 9 + p) * 4 + s) * 64 + lane];
            }
        }
        f32x4 accf = {0.f, 0.f, 0.f, 0.f};
        f32x4 accc = {0.f, 0.f, 0.f, 0.f};
        #pragma unroll
        for (int s = 0; s < 4; ++s) {
            accf = __builtin_amdgcn_mfma_f32_16x16x32_f16(af[s], fb[s], accf, 0, 0, 0);
            accc = __builtin_amdgcn_mfma_f32_16x16x32_f16(af[s], cb[s], accc, 0, 0, 0);
        }
        int row = m0 + quad * 4;
        int word = wbase + p * 16;
        #pragma unroll
        for (int i = 0; i < 4; ++i) {
            half2_t pk = __builtin_amdgcn_cvt_pkrtz(accf[i], accc[i]);
            dst[(size_t)(row + i) * 256 + word] = pk;
        }
        #pragma unroll
        for (int s = 0; s < 4; ++s) { fb[s] = nfb[s]; cb[s] = ncb[s]; }
    }
}

// ---------------- fused edge: MFMA contraction + LDS + gate + update --------
// Per block: one node, 2 waves. SINGLE-BARRIER structure: phase 1 computes
// BOTH halves' G into one 40-row LDS buffer (che rows 0..19, vdw 20..39);
// rows 20..31 of each half's 32-row MFMA product are dead (only quad 0's
// g1 rows 16..19 stored). Then ONE __syncthreads, then both activation loops.
#define GSTRIDE 132
__global__ __launch_bounds__(128)
void edge_kernel(const float* __restrict__ nodes_in, float* __restrict__ nodes_out,
                 _Float16* __restrict__ nodes_h,
                 const half2_t* __restrict__ Spk, const half2_t* __restrict__ Ypk,
                 const _Float16* __restrict__ rfrag,
                 const int* __restrict__ idx_che, const int* __restrict__ idx_vdw,
                 const _Float16* __restrict__ bwc,  // this layer: [2][16][64][8]
                 const float* __restrict__ bC) {    // [2][256]
    __shared__ half2_t G2[40 * GSTRIDE];            // 21.1 KB
    int t = threadIdx.x;
    int lane = t & 63;
    int wv = t >> 6;                                // 0..1
    int n = blockIdx.x;

    const int* ic = idx_che + (size_t)n * MM;
    const int* iv = idx_vdw + (size_t)n * MM;
    int jc[MM], jv[MM];
    #pragma unroll
    for (int m = 0; m < MM; ++m) jc[m] = ic[m];
    #pragma unroll
    for (int m = 0; m < MM; ++m) jv[m] = iv[m];

    // batch all 40 gathers up front (overlap the MFMA phase)
    half2_t yw[2 * MM];
    #pragma unroll
    for (int m = 0; m < MM; ++m) yw[m] = Ypk[(size_t)jc[m] * 256 + t];
    #pragma unroll
    for (int m = 0; m < MM; ++m) yw[MM + m] = Ypk[(size_t)jv[m] * 256 + 128 + t];

    half2_t spc = Spk[(size_t)n * 256 + t];
    half2_t spv = Spk[(size_t)n * 256 + 128 + t];
    float old = nodes_in[(size_t)n * HH + t];
    float sCf = bC[t] + (float)spc.x;
    float sCc = bC[128 + t] + (float)spc.y;
    float sVf = bC[256 + t] + (float)spv.x;
    float sVc = bC[384 + t] + (float)spv.y;

    const half2_t ONE0 = {(__fp16)1.f, (__fp16)0.f};
    const half2_t ZERO1 = {(__fp16)0.f, (__fp16)1.f};
    int quad = lane >> 4;
    int cla = lane & 15;
    float acc = 0.f;

    // ---- phase 1: both halves' MFMA contraction -> LDS (no barrier between)
    #pragma unroll
    for (int h = 0; h < 2; ++h) {
        const _Float16* rf = rfrag + ((size_t)(h * NN + n) * 2) * 512;
        f16x8 a0 = *(const f16x8*)(rf + lane * 8);
        f16x8 a1 = *(const f16x8*)(rf + 512 + lane * 8);
        const f16x8* bw = (const f16x8*)bwc + ((size_t)h * 16) * 64;
        int rbase = h * 20;
        #pragma unroll
        for (int p = 0; p < 4; ++p) {
            int pg = wv * 4 + p;                    // 0..7
            f16x8 bf = bw[(size_t)pg * 64 + lane];
            f16x8 bcfr = bw[(size_t)(8 + pg) * 64 + lane];
            f32x4 g0f = {0.f, 0.f, 0.f, 0.f};
            f32x4 g0c = {0.f, 0.f, 0.f, 0.f};
            f32x4 g1f = {0.f, 0.f, 0.f, 0.f};
            f32x4 g1c = {0.f, 0.f, 0.f, 0.f};
            g0f = __builtin_amdgcn_mfma_f32_16x16x32_f16(a0, bf, g0f, 0, 0, 0);
            g0c = __builtin_amdgcn_mfma_f32_16x16x32_f16(a0, bcfr, g0c, 0, 0, 0);
            g1f = __builtin_amdgcn_mfma_f32_16x16x32_f16(a1, bf, g1f, 0, 0, 0);
            g1c = __builtin_amdgcn_mfma_f32_16x16x32_f16(a1, bcfr, g1c, 0, 0, 0);
            int base = pg * 16 + cla;               // = t col
            #pragma unroll
            for (int i = 0; i < 4; ++i)
                G2[(rbase + quad * 4 + i) * GSTRIDE + base] = __builtin_amdgcn_cvt_pkrtz(g0f[i], g0c[i]);
            if (quad == 0) {
                #pragma unroll
                for (int i = 0; i < 4; ++i)
                    G2[(rbase + 16 + i) * GSTRIDE + base] = __builtin_amdgcn_cvt_pkrtz(g1f[i], g1c[i]);
            }
        }
    }
    __syncthreads();   // the ONLY barrier

    // ---- phase 2: activation over 40 edges ----
    #pragma unroll
    for (int m = 0; m < MM; ++m) {
        half2_t g = G2[m * GSTRIDE + t];
        half2_t w = yw[m];
        float gf = fdot2_(g, ONE0, fdot2_(w, ONE0, sCf));
        float gc = fdot2_(g, ZERO1, fdot2_(w, ZERO1, sCc));
        float uu = rcp_(1.f + exp2_(-gf));
        float p = log2_(1.f + exp2_(gc));
        p = (gc > 24.f) ? gc : p;
        acc = fmaf(p, uu, acc);
    }
    #pragma unroll
    for (int m = 0; m < MM; ++m) {
        half2_t g = G2[(20 + m) * GSTRIDE + t];
        half2_t w = yw[MM + m];
        float gf = fdot2_(g, ONE0, fdot2_(w, ONE0, sVf));
        float gc = fdot2_(g, ZERO1, fdot2_(w, ZERO1, sVc));
        float uu = rcp_(1.f + exp2_(-gf));
        float p = log2_(1.f + exp2_(gc));
        p = (gc > 24.f) ? gc : p;
        acc = fmaf(p, uu, acc);
    }
    float res = sp_(fmaf(acc, LN2_F, old));
    nodes_out[(size_t)n * HH + t] = res;
    nodes_h[(size_t)n * HH + t] = (_Float16)res;
}

// ---------------- pooling + head MLP ---------------------------------------
__global__ void pool_kernel(const float* __restrict__ nodes, const int* __restrict__ num_atoms,
                            const float* __restrict__ fc1_W, const float* __restrict__ fc1_b,
                            const float* __restrict__ out_W, const float* __restrict__ out_b,
                            float* __restrict__ out) {
    __shared__ float sh[HH];
    __shared__ float red[HH];
    int b = blockIdx.x, t = threadIdx.x;
    int start = 0;
    for (int i = 0; i < b; ++i) start += num_atoms[i];
    int cnt = num_atoms[b];
    float sum = 0.f;
    for (int a = 0; a < cnt; ++a) sum += nodes[(size_t)(start + a) * HH + t];
    float mean = sum / (float)cnt;
    sh[t] = sp_(mean);
    __syncthreads();
    float o = fc1_b[t];
    #pragma unroll 4
    for (int k = 0; k < HH; ++k) o = fmaf(sh[k], fc1_W[k * HH + t], o);
    red[t] = sp_(o) * out_W[t];
    __syncthreads();
    if (t == 0) {
        float tot = 0.f;
        for (int k = 0; k < HH; ++k) tot += red[k];
        out[b] = tot + out_b[0];
    }
}

// ---------------- launch ----------------------------------------------------
extern "C" void kernel_launch(void* const* d_in, const int* in_sizes, int n_in,
                              void* d_out, int out_size, void* d_ws, size_t ws_size,
                              hipStream_t stream) {
    const float* atoms_embed   = (const float*)d_in[0];
    const float* che_nbrs_fea  = (const float*)d_in[1];
    const float* vdw_nbrs_fea  = (const float*)d_in[2];
    const int*   che_nbrs_idx  = (const int*)  d_in[3];
    const int*   vdw_nbrs_idx  = (const int*)  d_in[4];
    const int*   num_atoms     = (const int*)  d_in[5];
    const float* emb_W         = (const float*)d_in[6];
    const float* emb_b         = (const float*)d_in[7];
    const float* che_filter_W  = (const float*)d_in[8];
    const float* che_filter_b  = (const float*)d_in[9];
    const float* che_fc_W      = (const float*)d_in[10];
    const float* che_fc_b      = (const float*)d_in[11];
    const float* vdw_filter_W  = (const float*)d_in[12];
    const float* vdw_filter_b  = (const float*)d_in[13];
    const float* vdw_fc_W      = (const float*)d_in[14];
    const float* vdw_fc_b      = (const float*)d_in[15];
    const float* fc1_W         = (const float*)d_in[16];
    const float* fc1_b         = (const float*)d_in[17];
    const float* out_W         = (const float*)d_in[18];
    const float* out_b         = (const float*)d_in[19];
    float* out = (float*)d_out;

    // workspace layout (~150 MB)
    float* w = (float*)d_ws;
    float* nodesA   = w;                                       // NN*HH f32
    float* nodesB   = nodesA + (size_t)NN * HH;                // NN*HH f32
    _Float16* nodes_h = (_Float16*)(nodesB + (size_t)NN * HH); // NN*HH f16
    half2_t* Spk    = (half2_t*)(nodes_h + (size_t)NN * HH);   // NN*256 words
    half2_t* Ypk    = Spk + (size_t)NN * 256;                  // NN*256 words
    _Float16* rfrag = (_Float16*)(Ypk + (size_t)NN * 256);     // 2*NN*2*512 f16
    _Float16* bpk   = rfrag + (size_t)2 * NN * 2 * 512;        // NCONV*131072 f16
    _Float16* bwc   = bpk + (size_t)NCONV * 131072;            // NCONV*2*16*512 f16
    float* bc       = (float*)(bwc + (size_t)NCONV * 2 * 16 * 512); // NCONV*512 f32

    // zero rfrag so every pad slot the edge MFMA touches is exact 0.0
    // (replay determinism: d_ws is re-poisoned 0xAA before every timed launch)
    hipMemsetAsync(rfrag, 0, (size_t)2 * NN * 2 * 512 * sizeof(_Float16), stream);

    prep_bias<<<dim3(1, 2, NCONV), 256, 0, stream>>>(
        che_filter_b, che_fc_W, che_fc_b, vdw_filter_b, vdw_fc_W, vdw_fc_b, bc);
    prep_bwc<<<dim3(16, 2, NCONV), 512, 0, stream>>>(
        che_filter_W, che_fc_W, vdw_filter_W, vdw_fc_W, bwc);
    prep_bpk<<<(NCONV * 128 * 1024 + 255) / 256, 256, 0, stream>>>(che_fc_W, vdw_fc_W, bpk);
    embed_kernel<<<NN, HH, 0, stream>>>(atoms_embed, emb_W, emb_b, nodesA, nodes_h);
    rbf_kernel<<<(2 * NN * MM + 255) / 256, 256, 0, stream>>>(che_nbrs_fea, vdw_nbrs_fea, rfrag);

    float* cur = nodesA;
    float* nxt = nodesB;
    for (int l = 0; l < NCONV; ++l) {
        gemm_mfma<<<NN / 16, 256, 0, stream>>>(nodes_h, bpk + (size_t)l * 131072, Spk, Ypk);
        edge_kernel<<<NN, HH, 0, stream>>>(
            cur, nxt, nodes_h, Spk, Ypk, rfrag, che_nbrs_idx, vdw_nbrs_idx,
            bwc + (size_t)l * 2 * 16 * 512, bc + (size_t)l * 512);
        float* tmp = cur; cur = nxt; nxt = tmp;
    }

    pool_kernel<<<BB, HH, 0, stream>>>(cur, num_atoms, fc1_W, fc1_b, out_W, out_b, out);
}

// Round 14
// 498.299 us; speedup vs baseline: 1.0509x; 1.0509x over previous
//
#include <hip/hip_runtime.h>
#include <hip/hip_bf16.h>
#include <math.h>

// Problem constants
#define NN 20000
#define MM 20          // neighbors (same for che and vdw)
#define EE 20          // RBF size
#define HH 128
#define BB 200
#define NCONV 3
#define CHE_CUT 8.0f
#define VDW_CUT 12.0f
#define PI_F 3.14159265358979323846f
#define LOG2E_F 1.44269504088896340736f
#define LN2_F 0.69314718055994530942f

// __builtin_amdgcn_cvt_pkrtz / __builtin_amdgcn_fdot2 use __fp16 vectors
typedef __fp16 half2_t __attribute__((ext_vector_type(2)));
// MFMA f16 builtins use _Float16 vectors
typedef _Float16 f16x8 __attribute__((ext_vector_type(8)));
typedef float f32x4 __attribute__((ext_vector_type(4)));

// ---------------- helpers ---------------------------------------------------
__device__ __forceinline__ float exp2_(float x) {
#if __has_builtin(__builtin_amdgcn_exp2f)
    return __builtin_amdgcn_exp2f(x);
#else
    return exp2f(x);
#endif
}
__device__ __forceinline__ float log2_(float x) {
#if __has_builtin(__builtin_amdgcn_logf)
    return __builtin_amdgcn_logf(x);
#else
    return log2f(x);
#endif
}
__device__ __forceinline__ float rcp_(float x) {
#if __has_builtin(__builtin_amdgcn_rcpf)
    return __builtin_amdgcn_rcpf(x);
#else
    return 1.f / x;
#endif
}
__device__ __forceinline__ float sp_(float x) {      // natural-domain softplus
    return (x > 15.f) ? x : LN2_F * log2_(1.f + exp2_(x * LOG2E_F));
}
__device__ __forceinline__ float fdot2_(half2_t a, half2_t b, float c) {
#if __has_builtin(__builtin_amdgcn_fdot2)
    return __builtin_amdgcn_fdot2(a, b, c, false);
#else
    return (float)a.x * (float)b.x + (float)a.y * (float)b.y + c;
#endif
}

// ---------------- prep: bc = (gb + fb @ gW_edge) * log2e --------------------
// bc layout: [l][half][gate*128+t] fp32
__global__ void prep_bias(const float* __restrict__ cfb, const float* __restrict__ cgW,
                          const float* __restrict__ cgb,
                          const float* __restrict__ vfb, const float* __restrict__ vgW,
                          const float* __restrict__ vgb, float* __restrict__ bc) {
    int half = blockIdx.y;
    int l = blockIdx.z;
    int j = threadIdx.x;         // 0..255
    const float* fb = half ? vfb : cfb;
    const float* gW = half ? vgW : cgW;
    const float* gb = half ? vgb : cgb;
    const float* gWe = gW + ((size_t)l * 384 + 128) * 256;
    const float* brow = fb + (size_t)l * HH;
    float acc = gb[(size_t)l * 256 + j];
    for (int k = 0; k < HH; ++k) acc = fmaf(brow[k], gWe[k * 256 + j], acc);
    bc[((size_t)l * 2 + half) * 256 + j] = acc * LOG2E_F;
}

// ---------------- prep: bwc — Wc=fW@gW_edge in MFMA B-fragment order --------
// PAIRED TILES: nt 0..7 = filt cols (t = nt*16+nc), nt 8..15 = core cols
// (same t) -> a wave computing tiles (p, 8+p) holds filt(t)/core(t) in ONE
// lane -> local cvt_pkrtz pack, no cross-lane traffic.
// k = e (0..19), pad 20..31 ZERO.
// bwc[l][h][nt(16)][lane(64)][8]: lane = (k>>3)*16 + nc, j = k&7
__global__ void prep_bwc(const float* __restrict__ cfW, const float* __restrict__ cgW,
                         const float* __restrict__ vfW, const float* __restrict__ vgW,
                         _Float16* __restrict__ bwc) {
    int nt = blockIdx.x;         // 0..15
    int half = blockIdx.y;
    int l = blockIdx.z;
    int tid = threadIdx.x;       // 0..511: k = tid>>4, nc = tid&15
    int k = tid >> 4, nc = tid & 15;
    int t = (nt & 7) * 16 + nc;          // 0..127
    int gcol = (nt >> 3) * 128 + t;      // filt: 0..127, core: 128..255
    const float* fW = half ? vfW : cfW;
    const float* gW = half ? vgW : cgW;
    const float* gWe = gW + ((size_t)l * 384 + 128) * 256;
    float val = 0.f;
    if (k < EE) {
        const float* frow = fW + ((size_t)l * EE + k) * HH;
        for (int kk = 0; kk < HH; ++kk) val = fmaf(frow[kk], gWe[kk * 256 + gcol], val);
        val *= LOG2E_F;
    }
    bwc[(((size_t)(l * 2 + half) * 16 + nt) * 64 + (k >> 3) * 16 + nc) * 8 + (k & 7)] = (_Float16)val;
}

// ---------------- prep: Bpk — B in MFMA B-fragment order, f16, x log2e ------
// column order (identity regions): [cheS|vdwS|cheY|vdwY]
__global__ void prep_bpk(const float* __restrict__ cgW, const float* __restrict__ vgW,
                         _Float16* __restrict__ bpk) {
    int i = blockIdx.x * 256 + threadIdx.x;
    if (i >= NCONV * 128 * 1024) return;
    int l = i >> 17;
    int rem = i & 131071;
    int k = rem >> 10;         // 0..127
    int c = rem & 1023;
    int half = (c >> 8) & 1;   // regions: che,vdw,che,vdw
    const float* src = half ? vgW : cgW;
    int grow = l * 384 + ((c < 512) ? k : 256 + k);
    float val = src[(size_t)grow * 256 + (c & 255)] * LOG2E_F;
    int nt = c >> 4, nc = c & 15;
    int s = k >> 5, kq = (k >> 3) & 3, j = k & 7;
    bpk[(size_t)l * 131072 + (((size_t)nt * 4 + s) * 64 + kq * 16 + nc) * 8 + j] = (_Float16)val;
}

// ---------------- embed: f32 nodes + f16 copy for the GEMM ------------------
__global__ void embed_kernel(const float* __restrict__ atoms, const float* __restrict__ W,
                             const float* __restrict__ bias, float* __restrict__ nodes,
                             _Float16* __restrict__ nodes_h) {
    int n = blockIdx.x, t = threadIdx.x;
    const float* arow = atoms + (size_t)n * 13;
    float acc = bias[t];
    #pragma unroll
    for (int k = 0; k < 13; ++k) acc = fmaf(arow[k], W[k * HH + t], acc);
    nodes[(size_t)n * HH + t] = acc;
    nodes_h[(size_t)n * HH + t] = (_Float16)acc;
}

// ---------------- rbf: write straight into per-node A-fragment order --------
// rfrag[h][n][mt(2)][lane(64)][8] f16;  A[m][k]: m=(lane&15)+16*mt, k=(lane>>4)*8+j
// k=20..31 explicit zeros; mt=1 rows 20..31 zero-filled by hipMemsetAsync.
__global__ void rbf_kernel(const float* __restrict__ che_fea, const float* __restrict__ vdw_fea,
                           _Float16* __restrict__ rfrag) {
    int i = blockIdx.x * blockDim.x + threadIdx.x;
    if (i >= 2 * NN * MM) return;
    bool isv = i >= NN * MM;
    int rem = isv ? i - NN * MM : i;
    int n = rem / MM, m = rem % MM;
    float d = isv ? vdw_fea[rem] : che_fea[rem];
    float cutoff = isv ? VDW_CUT : CHE_CUT;
    float x = d * (PI_F / cutoff);
    float s1 = sinf(x), c1 = cosf(x);
    float env = 0.5f * (c1 + 1.f);
    float scale = (d < cutoff) ? (env / d) : 0.f;
    float out[EE];
    float skm1 = 0.f, sk = s1;
    #pragma unroll
    for (int e = 0; e < EE; ++e) {
        out[e] = sk * scale;
        float nx = 2.f * c1 * sk - skm1;
        skm1 = sk; sk = nx;
    }
    int mt = m >> 4, la = m & 15;
    _Float16* base = rfrag + (((size_t)(isv ? NN + n : n) * 2 + mt) * 64) * 8 + la * 8;
    f16x8 v0, v1, v2, v3;
    #pragma unroll
    for (int j = 0; j < 8; ++j) {
        v0[j] = (_Float16)out[j];
        v1[j] = (_Float16)out[8 + j];
        v2[j] = (j < 4) ? (_Float16)out[16 + j] : (_Float16)0.f;
        v3[j] = (_Float16)0.f;
    }
    *(f16x8*)(base) = v0;             // quad 0 (k 0..7)
    *(f16x8*)(base + 128) = v1;       // quad 1 (k 8..15)
    *(f16x8*)(base + 256) = v2;       // quad 2 (k 16..23, 20+ zero)
    *(f16x8*)(base + 384) = v3;       // quad 3 (k 24..31, zero)
}

// ---------------- SY GEMM via MFMA: [N,128]@[128,1024] -> Spk + Ypk f16x2 ---
// 1250 blocks x 4 waves; M=16 rows/block. Wave wv handles gate pair tiles
// (wv*16+p, wv*16+8+p), p=0..7 -> (filt,core) of one channel in SAME lane.
// wv 0: che-S, 1: vdw-S, 2: che-Y, 3: vdw-Y. All values pre-scaled by log2e.
__global__ __launch_bounds__(256)
void gemm_mfma(const _Float16* __restrict__ Ah, const _Float16* __restrict__ Bpk,
               half2_t* __restrict__ Spk, half2_t* __restrict__ Ypk) {
    int lane = threadIdx.x & 63;
    int wv = threadIdx.x >> 6;       // 0..3
    int m0 = blockIdx.x * 16;
    int la = lane & 15;
    int quad = lane >> 4;
    int k0 = quad * 8;

    f16x8 af[4];
    {
        const _Float16* arow = Ah + (size_t)(m0 + la) * 128 + k0;
        #pragma unroll
        for (int s = 0; s < 4; ++s)
            af[s] = *(const f16x8*)(arow + s * 32);
    }

    const f16x8* bp = (const f16x8*)Bpk;
    int ntf0 = wv * 16;
    half2_t* dst = (wv & 2) ? Ypk : Spk;
    int wbase = (wv & 1) * 128 + la;

    f16x8 fb[4], cb[4], nfb[4], ncb[4];
    #pragma unroll
    for (int s = 0; s < 4; ++s) {
        fb[s] = bp[((size_t)ntf0 * 4 + s) * 64 + lane];
        cb[s] = bp[((size_t)(ntf0 + 8) * 4 + s) * 64 + lane];
    }
    for (int p = 0; p < 8; ++p) {
        if (p < 7) {
            #pragma unroll
            for (int s = 0; s < 4; ++s) {
                nfb[s] = bp[((size_t)(ntf0 + p + 1) * 4 + s) * 64 + lane];
                ncb[s] = bp[((size_t)(ntf0 + 9 + p) * 4 + s) * 64 + lane];
            }
        }
        f32x4 accf = {0.f, 0.f, 0.f, 0.f};
        f32x4 accc = {0.f, 0.f, 0.f, 0.f};
        #pragma unroll
        for (int s = 0; s < 4; ++s) {
            accf = __builtin_amdgcn_mfma_f32_16x16x32_f16(af[s], fb[s], accf, 0, 0, 0);
            accc = __builtin_amdgcn_mfma_f32_16x16x32_f16(af[s], cb[s], accc, 0, 0, 0);
        }
        int row = m0 + quad * 4;
        int word = wbase + p * 16;
        #pragma unroll
        for (int i = 0; i < 4; ++i) {
            half2_t pk = __builtin_amdgcn_cvt_pkrtz(accf[i], accc[i]);
            dst[(size_t)(row + i) * 256 + word] = pk;
        }
        #pragma unroll
        for (int s = 0; s < 4; ++s) { fb[s] = nfb[s]; cb[s] = ncb[s]; }
    }
}

// ---------------- fused edge: MFMA contraction + LDS + gate + update --------
// Per block: one node, 4 WAVES (256 threads). Phase 1: the 16 (half,pg)
// tile-pairs are split across the 4 waves (wave wv -> half wv>>1, pg
// (wv&1)*4+p). One barrier. Phase 2: threads t<128 do the 20 che edges of
// channel t; threads t>=128 do the 20 vdw edges of channel t-128 (halves
// the serial activation chain, doubles resident waves). Partial sums are
// combined through a small LDS buffer.
#define GSTRIDE 132
__global__ __launch_bounds__(256)
void edge_kernel(const float* __restrict__ nodes_in, float* __restrict__ nodes_out,
                 _Float16* __restrict__ nodes_h,
                 const half2_t* __restrict__ Spk, const half2_t* __restrict__ Ypk,
                 const _Float16* __restrict__ rfrag,
                 const int* __restrict__ idx_che, const int* __restrict__ idx_vdw,
                 const _Float16* __restrict__ bwc,  // this layer: [2][16][64][8]
                 const float* __restrict__ bC) {    // [2][256]
    __shared__ half2_t G2[40 * GSTRIDE];            // 21.1 KB
    __shared__ float red[HH];                       // vdw partial sums
    int t = threadIdx.x;                            // 0..255
    int lane = t & 63;
    int wv = t >> 6;                                // 0..3
    int n = blockIdx.x;
    int h2 = t >> 7;                                // 0 = che group, 1 = vdw
    int tc = t & 127;                               // channel

    // ---- per-group neighbor indices (wave-uniform -> s_load) ----
    const int* idxp = h2 ? (idx_vdw + (size_t)n * MM) : (idx_che + (size_t)n * MM);
    int jx[MM];
    #pragma unroll
    for (int m = 0; m < MM; ++m) jx[m] = idxp[m];

    // ---- batch this group's 20 gathers up front (overlap MFMA phase) ----
    half2_t yw[MM];
    #pragma unroll
    for (int m = 0; m < MM; ++m) yw[m] = Ypk[(size_t)jx[m] * 256 + h2 * 128 + tc];

    half2_t spx = Spk[(size_t)n * 256 + h2 * 128 + tc];
    float old = (h2 == 0) ? nodes_in[(size_t)n * HH + tc] : 0.f;
    float sf = bC[h2 * 256 + tc] + (float)spx.x;
    float sc = bC[h2 * 256 + 128 + tc] + (float)spx.y;

    const half2_t ONE0 = {(__fp16)1.f, (__fp16)0.f};
    const half2_t ZERO1 = {(__fp16)0.f, (__fp16)1.f};
    int quad = lane >> 4;
    int cla = lane & 15;

    // ---- phase 1: wave wv computes half hw = wv>>1, tiles pg = (wv&1)*4+p
    {
        int hw = wv >> 1;
        int rbase = hw * 20;
        const _Float16* rf = rfrag + ((size_t)(hw * NN + n) * 2) * 512;
        f16x8 a0 = *(const f16x8*)(rf + lane * 8);
        f16x8 a1 = *(const f16x8*)(rf + 512 + lane * 8);
        const f16x8* bw = (const f16x8*)bwc + ((size_t)hw * 16) * 64;
        #pragma unroll
        for (int p = 0; p < 4; ++p) {
            int pg = (wv & 1) * 4 + p;              // 0..7
            f16x8 bf = bw[(size_t)pg * 64 + lane];
            f16x8 bcfr = bw[(size_t)(8 + pg) * 64 + lane];
            f32x4 g0f = {0.f, 0.f, 0.f, 0.f};
            f32x4 g0c = {0.f, 0.f, 0.f, 0.f};
            f32x4 g1f = {0.f, 0.f, 0.f, 0.f};
            f32x4 g1c = {0.f, 0.f, 0.f, 0.f};
            g0f = __builtin_amdgcn_mfma_f32_16x16x32_f16(a0, bf, g0f, 0, 0, 0);
            g0c = __builtin_amdgcn_mfma_f32_16x16x32_f16(a0, bcfr, g0c, 0, 0, 0);
            g1f = __builtin_amdgcn_mfma_f32_16x16x32_f16(a1, bf, g1f, 0, 0, 0);
            g1c = __builtin_amdgcn_mfma_f32_16x16x32_f16(a1, bcfr, g1c, 0, 0, 0);
            int base = pg * 16 + cla;               // = channel col
            #pragma unroll
            for (int i = 0; i < 4; ++i)
                G2[(rbase + quad * 4 + i) * GSTRIDE + base] = __builtin_amdgcn_cvt_pkrtz(g0f[i], g0c[i]);
            if (quad == 0) {
                #pragma unroll
                for (int i = 0; i < 4; ++i)
                    G2[(rbase + 16 + i) * GSTRIDE + base] = __builtin_amdgcn_cvt_pkrtz(g1f[i], g1c[i]);
            }
        }
    }
    __syncthreads();

    // ---- phase 2: 20-edge activation chain per thread ----
    float acc = 0.f;
    int grow = h2 * 20;
    #pragma unroll
    for (int m = 0; m < MM; ++m) {
        half2_t g = G2[(grow + m) * GSTRIDE + tc];
        half2_t gw = g + yw[m];                     // packed f16 add
        float gf = fdot2_(gw, ONE0, sf);
        float gc = fdot2_(gw, ZERO1, sc);
        float uu = rcp_(1.f + exp2_(-gf));
        float p = log2_(1.f + exp2_(gc));
        p = (gc > 24.f) ? gc : p;
        acc = fmaf(p, uu, acc);
    }
    if (h2) red[tc] = acc;
    __syncthreads();
    if (!h2) {
        float res = sp_(fmaf(acc + red[tc], LN2_F, old));
        nodes_out[(size_t)n * HH + tc] = res;
        nodes_h[(size_t)n * HH + tc] = (_Float16)res;
    }
}

// ---------------- pooling + head MLP ---------------------------------------
__global__ void pool_kernel(const float* __restrict__ nodes, const int* __restrict__ num_atoms,
                            const float* __restrict__ fc1_W, const float* __restrict__ fc1_b,
                            const float* __restrict__ out_W, const float* __restrict__ out_b,
                            float* __restrict__ out) {
    __shared__ float sh[HH];
    __shared__ float red[HH];
    int b = blockIdx.x, t = threadIdx.x;
    int start = 0;
    for (int i = 0; i < b; ++i) start += num_atoms[i];
    int cnt = num_atoms[b];
    float sum = 0.f;
    for (int a = 0; a < cnt; ++a) sum += nodes[(size_t)(start + a) * HH + t];
    float mean = sum / (float)cnt;
    sh[t] = sp_(mean);
    __syncthreads();
    float o = fc1_b[t];
    #pragma unroll 4
    for (int k = 0; k < HH; ++k) o = fmaf(sh[k], fc1_W[k * HH + t], o);
    red[t] = sp_(o) * out_W[t];
    __syncthreads();
    if (t == 0) {
        float tot = 0.f;
        for (int k = 0; k < HH; ++k) tot += red[k];
        out[b] = tot + out_b[0];
    }
}

// ---------------- launch ----------------------------------------------------
extern "C" void kernel_launch(void* const* d_in, const int* in_sizes, int n_in,
                              void* d_out, int out_size, void* d_ws, size_t ws_size,
                              hipStream_t stream) {
    const float* atoms_embed   = (const float*)d_in[0];
    const float* che_nbrs_fea  = (const float*)d_in[1];
    const float* vdw_nbrs_fea  = (const float*)d_in[2];
    const int*   che_nbrs_idx  = (const int*)  d_in[3];
    const int*   vdw_nbrs_idx  = (const int*)  d_in[4];
    const int*   num_atoms     = (const int*)  d_in[5];
    const float* emb_W         = (const float*)d_in[6];
    const float* emb_b         = (const float*)d_in[7];
    const float* che_filter_W  = (const float*)d_in[8];
    const float* che_filter_b  = (const float*)d_in[9];
    const float* che_fc_W      = (const float*)d_in[10];
    const float* che_fc_b      = (const float*)d_in[11];
    const float* vdw_filter_W  = (const float*)d_in[12];
    const float* vdw_filter_b  = (const float*)d_in[13];
    const float* vdw_fc_W      = (const float*)d_in[14];
    const float* vdw_fc_b      = (const float*)d_in[15];
    const float* fc1_W         = (const float*)d_in[16];
    const float* fc1_b         = (const float*)d_in[17];
    const float* out_W         = (const float*)d_in[18];
    const float* out_b         = (const float*)d_in[19];
    float* out = (float*)d_out;

    // workspace layout (~150 MB)
    float* w = (float*)d_ws;
    float* nodesA   = w;                                       // NN*HH f32
    float* nodesB   = nodesA + (size_t)NN * HH;                // NN*HH f32
    _Float16* nodes_h = (_Float16*)(nodesB + (size_t)NN * HH); // NN*HH f16
    half2_t* Spk    = (half2_t*)(nodes_h + (size_t)NN * HH);   // NN*256 words
    half2_t* Ypk    = Spk + (size_t)NN * 256;                  // NN*256 words
    _Float16* rfrag = (_Float16*)(Ypk + (size_t)NN * 256);     // 2*NN*2*512 f16
    _Float16* bpk   = rfrag + (size_t)2 * NN * 2 * 512;        // NCONV*131072 f16
    _Float16* bwc   = bpk + (size_t)NCONV * 131072;            // NCONV*2*16*512 f16
    float* bc       = (float*)(bwc + (size_t)NCONV * 2 * 16 * 512); // NCONV*512 f32

    // zero rfrag so every pad slot the edge MFMA touches is exact 0.0
    // (replay determinism: d_ws is re-poisoned 0xAA before every timed launch)
    hipMemsetAsync(rfrag, 0, (size_t)2 * NN * 2 * 512 * sizeof(_Float16), stream);

    prep_bias<<<dim3(1, 2, NCONV), 256, 0, stream>>>(
        che_filter_b, che_fc_W, che_fc_b, vdw_filter_b, vdw_fc_W, vdw_fc_b, bc);
    prep_bwc<<<dim3(16, 2, NCONV), 512, 0, stream>>>(
        che_filter_W, che_fc_W, vdw_filter_W, vdw_fc_W, bwc);
    prep_bpk<<<(NCONV * 128 * 1024 + 255) / 256, 256, 0, stream>>>(che_fc_W, vdw_fc_W, bpk);
    embed_kernel<<<NN, HH, 0, stream>>>(atoms_embed, emb_W, emb_b, nodesA, nodes_h);
    rbf_kernel<<<(2 * NN * MM + 255) / 256, 256, 0, stream>>>(che_nbrs_fea, vdw_nbrs_fea, rfrag);

    float* cur = nodesA;
    float* nxt = nodesB;
    for (int l = 0; l < NCONV; ++l) {
        gemm_mfma<<<NN / 16, 256, 0, stream>>>(nodes_h, bpk + (size_t)l * 131072, Spk, Ypk);
        edge_kernel<<<NN, 256, 0, stream>>>(
            cur, nxt, nodes_h, Spk, Ypk, rfrag, che_nbrs_idx, vdw_nbrs_idx,
            bwc + (size_t)l * 2 * 16 * 512, bc + (size_t)l * 512);
        float* tmp = cur; cur = nxt; nxt = tmp;
    }

    pool_kernel<<<BB, HH, 0, stream>>>(cur, num_atoms, fc1_W, fc1_b, out_W, out_b, out);
}

// Round 16
// 487.837 us; speedup vs baseline: 1.0734x; 1.0214x over previous
//
#include <hip/hip_runtime.h>
#include <hip/hip_bf16.h>
#include <math.h>

// Problem constants
#define NN 20000
#define MM 20          // neighbors (same for che and vdw)
#define EE 20          // RBF size
#define HH 128
#define BB 200
#define NCONV 3
#define CHE_CUT 8.0f
#define VDW_CUT 12.0f
#define PI_F 3.14159265358979323846f
#define LOG2E_F 1.44269504088896340736f
#define LN2_F 0.69314718055994530942f

// __builtin_amdgcn_cvt_pkrtz / __builtin_amdgcn_fdot2 use __fp16 vectors
typedef __fp16 half2_t __attribute__((ext_vector_type(2)));
// MFMA f16 builtins use _Float16 vectors
typedef _Float16 f16x8 __attribute__((ext_vector_type(8)));
typedef float f32x4 __attribute__((ext_vector_type(4)));

// ---------------- helpers ---------------------------------------------------
__device__ __forceinline__ float exp2_(float x) {
#if __has_builtin(__builtin_amdgcn_exp2f)
    return __builtin_amdgcn_exp2f(x);
#else
    return exp2f(x);
#endif
}
__device__ __forceinline__ float log2_(float x) {
#if __has_builtin(__builtin_amdgcn_logf)
    return __builtin_amdgcn_logf(x);
#else
    return log2f(x);
#endif
}
__device__ __forceinline__ float rcp_(float x) {
#if __has_builtin(__builtin_amdgcn_rcpf)
    return __builtin_amdgcn_rcpf(x);
#else
    return 1.f / x;
#endif
}
__device__ __forceinline__ float sp_(float x) {      // natural-domain softplus
    return (x > 15.f) ? x : LN2_F * log2_(1.f + exp2_(x * LOG2E_F));
}
__device__ __forceinline__ float fdot2_(half2_t a, half2_t b, float c) {
#if __has_builtin(__builtin_amdgcn_fdot2)
    return __builtin_amdgcn_fdot2(a, b, c, false);
#else
    return (float)a.x * (float)b.x + (float)a.y * (float)b.y + c;
#endif
}

// ---------------- prep: bc = (gb + fb @ gW_edge) * log2e --------------------
// bc layout: [l][half][gate*128+t] fp32
__global__ void prep_bias(const float* __restrict__ cfb, const float* __restrict__ cgW,
                          const float* __restrict__ cgb,
                          const float* __restrict__ vfb, const float* __restrict__ vgW,
                          const float* __restrict__ vgb, float* __restrict__ bc) {
    int half = blockIdx.y;
    int l = blockIdx.z;
    int j = threadIdx.x;         // 0..255
    const float* fb = half ? vfb : cfb;
    const float* gW = half ? vgW : cgW;
    const float* gb = half ? vgb : cgb;
    const float* gWe = gW + ((size_t)l * 384 + 128) * 256;
    const float* brow = fb + (size_t)l * HH;
    float acc = gb[(size_t)l * 256 + j];
    for (int k = 0; k < HH; ++k) acc = fmaf(brow[k], gWe[k * 256 + j], acc);
    bc[((size_t)l * 2 + half) * 256 + j] = acc * LOG2E_F;
}

// ---------------- prep: bwc — Wc=fW@gW_edge in MFMA B-fragment order --------
// PAIRED TILES: nt 0..7 = filt cols (t = nt*16+nc), nt 8..15 = core cols
// (same t) -> a wave computing tiles (p, 8+p) holds filt(t)/core(t) in ONE
// lane -> local cvt_pkrtz pack, no cross-lane traffic.
// k = e (0..19), pad 20..31 ZERO.
// bwc[l][h][nt(16)][lane(64)][8]: lane = (k>>3)*16 + nc, j = k&7
__global__ void prep_bwc(const float* __restrict__ cfW, const float* __restrict__ cgW,
                         const float* __restrict__ vfW, const float* __restrict__ vgW,
                         _Float16* __restrict__ bwc) {
    int nt = blockIdx.x;         // 0..15
    int half = blockIdx.y;
    int l = blockIdx.z;
    int tid = threadIdx.x;       // 0..511: k = tid>>4, nc = tid&15
    int k = tid >> 4, nc = tid & 15;
    int t = (nt & 7) * 16 + nc;          // 0..127
    int gcol = (nt >> 3) * 128 + t;      // filt: 0..127, core: 128..255
    const float* fW = half ? vfW : cfW;
    const float* gW = half ? vgW : cgW;
    const float* gWe = gW + ((size_t)l * 384 + 128) * 256;
    float val = 0.f;
    if (k < EE) {
        const float* frow = fW + ((size_t)l * EE + k) * HH;
        for (int kk = 0; kk < HH; ++kk) val = fmaf(frow[kk], gWe[kk * 256 + gcol], val);
        val *= LOG2E_F;
    }
    bwc[(((size_t)(l * 2 + half) * 16 + nt) * 64 + (k >> 3) * 16 + nc) * 8 + (k & 7)] = (_Float16)val;
}

// ---------------- prep: Bpk — B in MFMA B-fragment order, f16, x log2e ------
// column order (identity regions): [cheS|vdwS|cheY|vdwY]
__global__ void prep_bpk(const float* __restrict__ cgW, const float* __restrict__ vgW,
                         _Float16* __restrict__ bpk) {
    int i = blockIdx.x * 256 + threadIdx.x;
    if (i >= NCONV * 128 * 1024) return;
    int l = i >> 17;
    int rem = i & 131071;
    int k = rem >> 10;         // 0..127
    int c = rem & 1023;
    int half = (c >> 8) & 1;   // regions: che,vdw,che,vdw
    const float* src = half ? vgW : cgW;
    int grow = l * 384 + ((c < 512) ? k : 256 + k);
    float val = src[(size_t)grow * 256 + (c & 255)] * LOG2E_F;
    int nt = c >> 4, nc = c & 15;
    int s = k >> 5, kq = (k >> 3) & 3, j = k & 7;
    bpk[(size_t)l * 131072 + (((size_t)nt * 4 + s) * 64 + kq * 16 + nc) * 8 + j] = (_Float16)val;
}

// ---------------- embed: f32 nodes + f16 copy for the GEMM ------------------
__global__ void embed_kernel(const float* __restrict__ atoms, const float* __restrict__ W,
                             const float* __restrict__ bias, float* __restrict__ nodes,
                             _Float16* __restrict__ nodes_h) {
    int n = blockIdx.x, t = threadIdx.x;
    const float* arow = atoms + (size_t)n * 13;
    float acc = bias[t];
    #pragma unroll
    for (int k = 0; k < 13; ++k) acc = fmaf(arow[k], W[k * HH + t], acc);
    nodes[(size_t)n * HH + t] = acc;
    nodes_h[(size_t)n * HH + t] = (_Float16)acc;
}

// ---------------- rbf: write straight into per-node A-fragment order --------
// rfrag[h][n][mt(2)][lane(64)][8] f16;  A[m][k]: m=(lane&15)+16*mt, k=(lane>>4)*8+j
// k=20..31 explicit zeros. Pad slots (mt=1 lanes la>=4, i.e. rows 20..31)
// are zero-written by the tail threads of THIS kernel every launch (replay
// determinism — R9 tripwire; no blanket memset needed).
__global__ void rbf_kernel(const float* __restrict__ che_fea, const float* __restrict__ vdw_fea,
                           _Float16* __restrict__ rfrag) {
    int i = blockIdx.x * blockDim.x + threadIdx.x;
    if (i >= 2 * NN * MM) {
        // tail: zero the pad rows. j indexes [h*NN+n]x[la 4..15]
        int j = i - 2 * NN * MM;
        if (j >= 2 * NN * 12) return;
        int la = 4 + (j % 12);
        int hn = j / 12;          // 0 .. 2*NN-1  (= h*NN + n)
        _Float16* base = rfrag + (((size_t)hn * 2 + 1) * 64) * 8 + la * 8;
        f16x8 z = {};
        *(f16x8*)(base) = z;
        *(f16x8*)(base + 128) = z;
        *(f16x8*)(base + 256) = z;
        *(f16x8*)(base + 384) = z;
        return;
    }
    bool isv = i >= NN * MM;
    int rem = isv ? i - NN * MM : i;
    int n = rem / MM, m = rem % MM;
    float d = isv ? vdw_fea[rem] : che_fea[rem];
    float cutoff = isv ? VDW_CUT : CHE_CUT;
    float x = d * (PI_F / cutoff);
    float s1 = sinf(x), c1 = cosf(x);
    float env = 0.5f * (c1 + 1.f);
    float scale = (d < cutoff) ? (env / d) : 0.f;
    float out[EE];
    float skm1 = 0.f, sk = s1;
    #pragma unroll
    for (int e = 0; e < EE; ++e) {
        out[e] = sk * scale;
        float nx = 2.f * c1 * sk - skm1;
        skm1 = sk; sk = nx;
    }
    int mt = m >> 4, la = m & 15;
    _Float16* base = rfrag + (((size_t)(isv ? NN + n : n) * 2 + mt) * 64) * 8 + la * 8;
    f16x8 v0, v1, v2, v3;
    #pragma unroll
    for (int j = 0; j < 8; ++j) {
        v0[j] = (_Float16)out[j];
        v1[j] = (_Float16)out[8 + j];
        v2[j] = (j < 4) ? (_Float16)out[16 + j] : (_Float16)0.f;
        v3[j] = (_Float16)0.f;
    }
    *(f16x8*)(base) = v0;             // quad 0 (k 0..7)
    *(f16x8*)(base + 128) = v1;       // quad 1 (k 8..15)
    *(f16x8*)(base + 256) = v2;       // quad 2 (k 16..23, 20+ zero)
    *(f16x8*)(base + 384) = v3;       // quad 3 (k 24..31, zero)
}

// ---------------- SY GEMM via MFMA: [N,128]@[128,1024] -> Spk + Ypk f16x2 ---
// 1250 blocks x 4 waves; M=16 rows/block. Wave wv handles gate pair tiles
// (wv*16+p, wv*16+8+p), p=0..7 -> (filt,core) of one channel in SAME lane.
// wv 0: che-S, 1: vdw-S, 2: che-Y, 3: vdw-Y. All values pre-scaled by log2e.
__global__ __launch_bounds__(256)
void gemm_mfma(const _Float16* __restrict__ Ah, const _Float16* __restrict__ Bpk,
               half2_t* __restrict__ Spk, half2_t* __restrict__ Ypk) {
    int lane = threadIdx.x & 63;
    int wv = threadIdx.x >> 6;       // 0..3
    int m0 = blockIdx.x * 16;
    int la = lane & 15;
    int quad = lane >> 4;
    int k0 = quad * 8;

    f16x8 af[4];
    {
        const _Float16* arow = Ah + (size_t)(m0 + la) * 128 + k0;
        #pragma unroll
        for (int s = 0; s < 4; ++s)
            af[s] = *(const f16x8*)(arow + s * 32);
    }

    const f16x8* bp = (const f16x8*)Bpk;
    int ntf0 = wv * 16;
    half2_t* dst = (wv & 2) ? Ypk : Spk;
    int wbase = (wv & 1) * 128 + la;

    f16x8 fb[4], cb[4], nfb[4], ncb[4];
    #pragma unroll
    for (int s = 0; s < 4; ++s) {
        fb[s] = bp[((size_t)ntf0 * 4 + s) * 64 + lane];
        cb[s] = bp[((size_t)(ntf0 + 8) * 4 + s) * 64 + lane];
    }
    for (int p = 0; p < 8; ++p) {
        if (p < 7) {
            #pragma unroll
            for (int s = 0; s < 4; ++s) {
                nfb[s] = bp[((size_t)(ntf0 + p + 1) * 4 + s) * 64 + lane];
                ncb[s] = bp[((size_t)(ntf0 + 9 + p) * 4 + s) * 64 + lane];
            }
        }
        f32x4 accf = {0.f, 0.f, 0.f, 0.f};
        f32x4 accc = {0.f, 0.f, 0.f, 0.f};
        #pragma unroll
        for (int s = 0; s < 4; ++s) {
            accf = __builtin_amdgcn_mfma_f32_16x16x32_f16(af[s], fb[s], accf, 0, 0, 0);
            accc = __builtin_amdgcn_mfma_f32_16x16x32_f16(af[s], cb[s], accc, 0, 0, 0);
        }
        int row = m0 + quad * 4;
        int word = wbase + p * 16;
        #pragma unroll
        for (int i = 0; i < 4; ++i) {
            half2_t pk = __builtin_amdgcn_cvt_pkrtz(accf[i], accc[i]);
            dst[(size_t)(row + i) * 256 + word] = pk;
        }
        #pragma unroll
        for (int s = 0; s < 4; ++s) { fb[s] = nfb[s]; cb[s] = ncb[s]; }
    }
}

// ---------------- fused edge: MFMA contraction + LDS + gate + update --------
// Per block: one node, 4 WAVES (256 threads). Phase 1: the 16 (half,pg)
// tile-pairs are split across the 4 waves. One barrier. Phase 2: threads
// t<128 do 20 che edges of channel t; threads >=128 do 20 vdw edges.
// NOTE: the (gc>24) select is REQUIRED: for gc >= 128, log2(1+exp2(gc))
// = inf while sig(gf) can be exactly 0 -> fmaf(inf, 0, acc) = NaN.
// Real gate values DO reach that regime (R15 NaN post-mortem).
#define GSTRIDE 132
__global__ __launch_bounds__(256)
void edge_kernel(const float* __restrict__ nodes_in, float* __restrict__ nodes_out,
                 _Float16* __restrict__ nodes_h,
                 const half2_t* __restrict__ Spk, const half2_t* __restrict__ Ypk,
                 const _Float16* __restrict__ rfrag,
                 const int* __restrict__ idx_che, const int* __restrict__ idx_vdw,
                 const _Float16* __restrict__ bwc,  // this layer: [2][16][64][8]
                 const float* __restrict__ bC) {    // [2][256]
    __shared__ half2_t G2[40 * GSTRIDE];            // 21.1 KB
    __shared__ float red[HH];                       // vdw partial sums
    int t = threadIdx.x;                            // 0..255
    int lane = t & 63;
    int wv = t >> 6;                                // 0..3
    int n = blockIdx.x;
    int h2 = t >> 7;                                // 0 = che group, 1 = vdw
    int tc = t & 127;                               // channel

    // ---- per-group neighbor indices (wave-uniform -> s_load) ----
    const int* idxp = h2 ? (idx_vdw + (size_t)n * MM) : (idx_che + (size_t)n * MM);
    int jx[MM];
    #pragma unroll
    for (int m = 0; m < MM; ++m) jx[m] = idxp[m];

    // ---- batch this group's 20 gathers up front (overlap MFMA phase) ----
    half2_t yw[MM];
    #pragma unroll
    for (int m = 0; m < MM; ++m) yw[m] = Ypk[(size_t)jx[m] * 256 + h2 * 128 + tc];

    half2_t spx = Spk[(size_t)n * 256 + h2 * 128 + tc];
    float old = (h2 == 0) ? nodes_in[(size_t)n * HH + tc] : 0.f;
    float sf = bC[h2 * 256 + tc] + (float)spx.x;
    float sc = bC[h2 * 256 + 128 + tc] + (float)spx.y;

    const half2_t ONE0 = {(__fp16)1.f, (__fp16)0.f};
    const half2_t ZERO1 = {(__fp16)0.f, (__fp16)1.f};
    int quad = lane >> 4;
    int cla = lane & 15;

    // ---- phase 1: wave wv computes half hw = wv>>1, tiles pg = (wv&1)*4+p
    {
        int hw = wv >> 1;
        int rbase = hw * 20;
        const _Float16* rf = rfrag + ((size_t)(hw * NN + n) * 2) * 512;
        f16x8 a0 = *(const f16x8*)(rf + lane * 8);
        f16x8 a1 = *(const f16x8*)(rf + 512 + lane * 8);
        const f16x8* bw = (const f16x8*)bwc + ((size_t)hw * 16) * 64;
        #pragma unroll
        for (int p = 0; p < 4; ++p) {
            int pg = (wv & 1) * 4 + p;              // 0..7
            f16x8 bf = bw[(size_t)pg * 64 + lane];
            f16x8 bcfr = bw[(size_t)(8 + pg) * 64 + lane];
            f32x4 g0f = {0.f, 0.f, 0.f, 0.f};
            f32x4 g0c = {0.f, 0.f, 0.f, 0.f};
            f32x4 g1f = {0.f, 0.f, 0.f, 0.f};
            f32x4 g1c = {0.f, 0.f, 0.f, 0.f};
            g0f = __builtin_amdgcn_mfma_f32_16x16x32_f16(a0, bf, g0f, 0, 0, 0);
            g0c = __builtin_amdgcn_mfma_f32_16x16x32_f16(a0, bcfr, g0c, 0, 0, 0);
            g1f = __builtin_amdgcn_mfma_f32_16x16x32_f16(a1, bf, g1f, 0, 0, 0);
            g1c = __builtin_amdgcn_mfma_f32_16x16x32_f16(a1, bcfr, g1c, 0, 0, 0);
            int base = pg * 16 + cla;               // = channel col
            #pragma unroll
            for (int i = 0; i < 4; ++i)
                G2[(rbase + quad * 4 + i) * GSTRIDE + base] = __builtin_amdgcn_cvt_pkrtz(g0f[i], g0c[i]);
            if (quad == 0) {
                #pragma unroll
                for (int i = 0; i < 4; ++i)
                    G2[(rbase + 16 + i) * GSTRIDE + base] = __builtin_amdgcn_cvt_pkrtz(g1f[i], g1c[i]);
            }
        }
    }
    __syncthreads();

    // ---- phase 2: 20-edge activation chain per thread ----
    float acc = 0.f;
    const half2_t* gp = &G2[(h2 * 20) * GSTRIDE + tc];
    #pragma unroll
    for (int m = 0; m < MM; ++m) {
        half2_t gw = gp[m * GSTRIDE] + yw[m];       // packed f16 add
        float gf = fdot2_(gw, ONE0, sf);
        float gc = fdot2_(gw, ZERO1, sc);
        float uu = rcp_(1.f + exp2_(-gf));
        float p = log2_(1.f + exp2_(gc));
        p = (gc > 24.f) ? gc : p;                   // inf*0 NaN guard (see note)
        acc = fmaf(p, uu, acc);
    }
    if (h2) red[tc] = acc;
    __syncthreads();
    if (!h2) {
        float res = sp_(fmaf(acc + red[tc], LN2_F, old));
        nodes_out[(size_t)n * HH + tc] = res;
        nodes_h[(size_t)n * HH + tc] = (_Float16)res;
    }
}

// ---------------- pooling + head MLP ---------------------------------------
__global__ void pool_kernel(const float* __restrict__ nodes, const int* __restrict__ num_atoms,
                            const float* __restrict__ fc1_W, const float* __restrict__ fc1_b,
                            const float* __restrict__ out_W, const float* __restrict__ out_b,
                            float* __restrict__ out) {
    __shared__ float sh[HH];
    __shared__ float red[HH];
    int b = blockIdx.x, t = threadIdx.x;
    int start = 0;
    for (int i = 0; i < b; ++i) start += num_atoms[i];
    int cnt = num_atoms[b];
    float sum = 0.f;
    for (int a = 0; a < cnt; ++a) sum += nodes[(size_t)(start + a) * HH + t];
    float mean = sum / (float)cnt;
    sh[t] = sp_(mean);
    __syncthreads();
    float o = fc1_b[t];
    #pragma unroll 4
    for (int k = 0; k < HH; ++k) o = fmaf(sh[k], fc1_W[k * HH + t], o);
    red[t] = sp_(o) * out_W[t];
    __syncthreads();
    if (t == 0) {
        float tot = 0.f;
        for (int k = 0; k < HH; ++k) tot += red[k];
        out[b] = tot + out_b[0];
    }
}

// ---------------- launch ----------------------------------------------------
extern "C" void kernel_launch(void* const* d_in, const int* in_sizes, int n_in,
                              void* d_out, int out_size, void* d_ws, size_t ws_size,
                              hipStream_t stream) {
    const float* atoms_embed   = (const float*)d_in[0];
    const float* che_nbrs_fea  = (const float*)d_in[1];
    const float* vdw_nbrs_fea  = (const float*)d_in[2];
    const int*   che_nbrs_idx  = (const int*)  d_in[3];
    const int*   vdw_nbrs_idx  = (const int*)  d_in[4];
    const int*   num_atoms     = (const int*)  d_in[5];
    const float* emb_W         = (const float*)d_in[6];
    const float* emb_b         = (const float*)d_in[7];
    const float* che_filter_W  = (const float*)d_in[8];
    const float* che_filter_b  = (const float*)d_in[9];
    const float* che_fc_W      = (const float*)d_in[10];
    const float* che_fc_b      = (const float*)d_in[11];
    const float* vdw_filter_W  = (const float*)d_in[12];
    const float* vdw_filter_b  = (const float*)d_in[13];
    const float* vdw_fc_W      = (const float*)d_in[14];
    const float* vdw_fc_b      = (const float*)d_in[15];
    const float* fc1_W         = (const float*)d_in[16];
    const float* fc1_b         = (const float*)d_in[17];
    const float* out_W         = (const float*)d_in[18];
    const float* out_b         = (const float*)d_in[19];
    float* out = (float*)d_out;

    // workspace layout (~150 MB)
    float* w = (float*)d_ws;
    float* nodesA   = w;                                       // NN*HH f32
    float* nodesB   = nodesA + (size_t)NN * HH;                // NN*HH f32
    _Float16* nodes_h = (_Float16*)(nodesB + (size_t)NN * HH); // NN*HH f16
    half2_t* Spk    = (half2_t*)(nodes_h + (size_t)NN * HH);   // NN*256 words
    half2_t* Ypk    = Spk + (size_t)NN * 256;                  // NN*256 words
    _Float16* rfrag = (_Float16*)(Ypk + (size_t)NN * 256);     // 2*NN*2*512 f16
    _Float16* bpk   = rfrag + (size_t)2 * NN * 2 * 512;        // NCONV*131072 f16
    _Float16* bwc   = bpk + (size_t)NCONV * 131072;            // NCONV*2*16*512 f16
    float* bc       = (float*)(bwc + (size_t)NCONV * 2 * 16 * 512); // NCONV*512 f32

    prep_bias<<<dim3(1, 2, NCONV), 256, 0, stream>>>(
        che_filter_b, che_fc_W, che_fc_b, vdw_filter_b, vdw_fc_W, vdw_fc_b, bc);
    prep_bwc<<<dim3(16, 2, NCONV), 512, 0, stream>>>(
        che_filter_W, che_fc_W, vdw_filter_W, vdw_fc_W, bwc);
    prep_bpk<<<(NCONV * 128 * 1024 + 255) / 256, 256, 0, stream>>>(che_fc_W, vdw_fc_W, bpk);
    embed_kernel<<<NN, HH, 0, stream>>>(atoms_embed, emb_W, emb_b, nodesA, nodes_h);
    // rbf grid covers data threads (2*NN*MM) + pad-zero tail (2*NN*12)
    rbf_kernel<<<(2 * NN * MM + 2 * NN * 12 + 255) / 256, 256, 0, stream>>>(
        che_nbrs_fea, vdw_nbrs_fea, rfrag);

    float* cur = nodesA;
    float* nxt = nodesB;
    for (int l = 0; l < NCONV; ++l) {
        gemm_mfma<<<NN / 16, 256, 0, stream>>>(nodes_h, bpk + (size_t)l * 131072, Spk, Ypk);
        edge_kernel<<<NN, 256, 0, stream>>>(
            cur, nxt, nodes_h, Spk, Ypk, rfrag, che_nbrs_idx, vdw_nbrs_idx,
            bwc + (size_t)l * 2 * 16 * 512, bc + (size_t)l * 512);
        float* tmp = cur; cur = nxt; nxt = tmp;
    }

    pool_kernel<<<BB, HH, 0, stream>>>(cur, num_atoms, fc1_W, fc1_b, out_W, out_b, out);
}